// Round 4
// baseline (142.757 us; speedup 1.0000x reference)
//
#include <hip/hip_runtime.h>
#include <cstddef>

// N=8, C=128, L=512, D=64, F=512, ATTN_W=64

// ---------------------------------------------------------------------------
// Kernel 1: prep = transpose_in + q/k projection.
// grid 256 (= N * L/16), block 256.
// ---------------------------------------------------------------------------
__global__ __launch_bounds__(256) void prep_kernel(
    const float* __restrict__ x, const float* __restrict__ Wt,
    const float* __restrict__ Wx, float* __restrict__ xt,
    float* __restrict__ q, float* __restrict__ k) {
  __shared__ float xs[128][17];
  int tid = threadIdx.x;
  int n = blockIdx.x >> 5;
  int l0 = (blockIdx.x & 31) << 4;

  for (int idx = tid; idx < 512; idx += 256) {
    int c = idx >> 2, v = idx & 3;
    float4 d4 = *(const float4*)(x + ((size_t)n * 128 + c) * 512 + l0 + 4 * v);
    xs[c][4 * v + 0] = d4.x; xs[c][4 * v + 1] = d4.y;
    xs[c][4 * v + 2] = d4.z; xs[c][4 * v + 3] = d4.w;
  }
  __syncthreads();

  for (int idx = tid; idx < 2048; idx += 256) {
    int c = idx & 127, jj = idx >> 7;
    xt[((size_t)n * 512 + l0 + jj) * 128 + c] = xs[c][jj];
  }

  int r = tid >> 4;
  int g = tid & 15;
  const float* W = (g < 8) ? Wt : Wx;
  float* dst = (g < 8) ? q : k;
  int f0 = (g & 7) << 3;
  float acc[8];
#pragma unroll
  for (int i = 0; i < 8; i++) acc[i] = 0.f;
#pragma unroll 4
  for (int cc = 0; cc < 128; cc++) {
    float xv = xs[cc][r];
    float4 w0 = *(const float4*)(W + cc * 64 + f0);
    float4 w1 = *(const float4*)(W + cc * 64 + f0 + 4);
    acc[0] += xv * w0.x; acc[1] += xv * w0.y; acc[2] += xv * w0.z; acc[3] += xv * w0.w;
    acc[4] += xv * w1.x; acc[5] += xv * w1.y; acc[6] += xv * w1.z; acc[7] += xv * w1.w;
  }
  float* dp = dst + ((size_t)n * 512 + l0 + r) * 64 + f0;
  *(float4*)dp = make_float4(acc[0], acc[1], acc[2], acc[3]);
  *(float4*)(dp + 4) = make_float4(acc[4], acc[5], acc[6], acc[7]);
}

// ---------------------------------------------------------------------------
// Kernel 2: FUSED banded attention scores + softmax + a-write + v=a@xt +
// residual + LN0 -> x2. grid 1024 (= N*L/4), block 256 (4 waves, 1 row/wave
// for scores; 2 rows per thread-pair for AV). LDS ~22 KB -> 4 blocks/CU.
// In-band max valid: denom >= 1, eps rescale error ~1e-5 << threshold.
// ---------------------------------------------------------------------------
__global__ __launch_bounds__(256) void attn_fused_kernel(
    const float* __restrict__ q, const float* __restrict__ k,
    const float* __restrict__ bh, const float* __restrict__ Wa,
    const float* __restrict__ ba, const float* __restrict__ xt,
    const float* __restrict__ g0, const float* __restrict__ be0,
    float* __restrict__ a, float* __restrict__ x2) {
  __shared__ float ks[67][65];
  __shared__ float qs[4][64];
  __shared__ float was[64];
  __shared__ float av[4][64];
  __shared__ float ys[4][128];
  int tid = threadIdx.x;
  int w = tid >> 6, lane = tid & 63;
  int n = blockIdx.x >> 7;
  int i0 = (blockIdx.x & 127) << 2;
  int i = i0 + w;
  int jlo0 = i0 - 32;

  if (tid < 64) was[tid] = Wa[tid];
  qs[w][lane] = q[((size_t)n * 512 + i) * 64 + lane] + bh[lane];

  // stage k window (67 rows x 64 d)
  for (int idx = tid; idx < 67 * 64; idx += 256) {
    int row = idx >> 6, d = idx & 63;
    int j = jlo0 + row;
    ks[row][d] = (j >= 0 && j < 512) ? k[((size_t)n * 512 + j) * 64 + d] : 0.f;
  }
  __syncthreads();

  // scores: wave w = row i0+w; lane = band position
  int j = jlo0 + w + lane;
  bool valid = (j >= 0 && j < 512);
  const float* krow = &ks[w + lane][0];
  float e = 0.f;
#pragma unroll 8
  for (int d = 0; d < 64; d++) {
    float hx = qs[w][d] + krow[d];
    float ex2 = __expf(2.f * hx);
    float th = 1.f - 2.f * __builtin_amdgcn_rcpf(ex2 + 1.f);  // tanh
    e += was[d] * th;
  }
  e += ba[0];
  if (!valid) e = -1e30f;

  float m = e;
  for (int o = 32; o > 0; o >>= 1) m = fmaxf(m, __shfl_xor(m, o, 64));
  float ex = valid ? __expf(e - m) : 0.f;
  float s = ex;
  for (int o = 32; o > 0; o >>= 1) s += __shfl_xor(s, o, 64);
  av[w][lane] = ex / (s + 1e-6f);

  // write full a row (zeros outside band)
  {
    float* arow = a + ((size_t)n * 512 + i) * 512;
    int jlo = i - 32;
#pragma unroll
    for (int t = 0; t < 2; t++) {
      int col0 = 4 * lane + 256 * t;
      float4 v;
      { int jr = col0 + 0 - jlo; int jc = min(max(jr, 0), 63); v.x = (jr >= 0 && jr < 64) ? av[w][jc] : 0.f; }
      { int jr = col0 + 1 - jlo; int jc = min(max(jr, 0), 63); v.y = (jr >= 0 && jr < 64) ? av[w][jc] : 0.f; }
      { int jr = col0 + 2 - jlo; int jc = min(max(jr, 0), 63); v.z = (jr >= 0 && jr < 64) ? av[w][jc] : 0.f; }
      { int jr = col0 + 3 - jlo; int jc = min(max(jr, 0), 63); v.w = (jr >= 0 && jr < 64) ? av[w][jc] : 0.f; }
      *(float4*)(arow + col0) = v;
    }
  }
  __syncthreads();  // av[] ready for all 4 rows

  // AV phase: thread = (c, h); rows 2h and 2h+1 share 65 xt loads.
  {
    int c = tid & 127;
    int h = tid >> 7;
    int r0 = 2 * h;
    const float* xtn = xt + (size_t)n * 512 * 128;
    float acc0 = 0.f, acc1 = 0.f;
    float res0 = 0.f, res1 = 0.f;
#pragma unroll 8
    for (int mm = 0; mm <= 64; mm++) {
      int jj = jlo0 + r0 + mm;
      int jc = min(max(jj, 0), 511);
      float xv = xtn[(size_t)jc * 128 + c];
      if (mm == 32) res0 = xv;         // xt row i0+r0
      if (mm == 33) res1 = xv;         // xt row i0+r0+1
      if (mm < 64) acc0 += av[r0][mm] * xv;
      if (mm >= 1) acc1 += av[r0 + 1][mm - 1] * xv;
    }
    ys[r0][c] = acc0 + res0;
    ys[r0 + 1][c] = acc1 + res1;
  }
  __syncthreads();

  // LN0: wave w = row w
  {
    float a0 = ys[w][lane], a1 = ys[w][lane + 64];
    float s0 = a0 + a1, s2 = a0 * a0 + a1 * a1;
    for (int o = 32; o > 0; o >>= 1) {
      s0 += __shfl_xor(s0, o, 64);
      s2 += __shfl_xor(s2, o, 64);
    }
    float mu = s0 * (1.f / 128.f);
    float var = s2 * (1.f / 128.f) - mu * mu;
    float rs = rsqrtf(var + 1e-5f);
    float* xrow = x2 + ((size_t)n * 512 + i) * 128;
    xrow[lane] = (a0 - mu) * rs * g0[lane] + be0[lane];
    xrow[lane + 64] = (a1 - mu) * rs * g0[lane + 64] + be0[lane + 64];
  }
}

// ---------------------------------------------------------------------------
// Kernel 3: FFN + residual + LN1 + transposed write -> out (N,C,L).
// 8 rows/block, grid 512. GEMM1: 4r x 4 consecutive f (b128 W0 loads).
// GEMM2: K-split x4, LDS partial reduce. Transpose fused.
// ---------------------------------------------------------------------------
__global__ __launch_bounds__(256) void ffn_ln_kernel(
    const float* __restrict__ x2, const float* __restrict__ W0,
    const float* __restrict__ b0, const float* __restrict__ W1,
    const float* __restrict__ b1, const float* __restrict__ g1,
    const float* __restrict__ be1, float* __restrict__ out) {
  __shared__ float xst[128][12];
  __shared__ float tst[512][12];
  __shared__ float part[4][8][128];
  __shared__ float ys[8][128];
  int tid = threadIdx.x;
  size_t rbase = (size_t)blockIdx.x * 8;

  for (int idx = tid; idx < 1024; idx += 256) {
    int r = idx >> 7, c = idx & 127;
    xst[c][r] = x2[(rbase + r) * 128 + c];
  }
  __syncthreads();

  // GEMM1 + bias + relu -> tst. Thread = rows r0..r0+3 x f0..f0+3.
  {
    int f0 = (tid & 127) << 2;
    int r0 = (tid >> 7) << 2;
    float acc[4][4];
#pragma unroll
    for (int i = 0; i < 4; i++)
#pragma unroll
      for (int jj = 0; jj < 4; jj++) acc[i][jj] = 0.f;
#pragma unroll 4
    for (int cc = 0; cc < 128; cc++) {
      float4 xv = *(const float4*)(&xst[cc][r0]);           // broadcast
      float4 wv = *(const float4*)(W0 + cc * 512 + f0);      // b128, 1KB/wave
      acc[0][0] += xv.x * wv.x; acc[0][1] += xv.x * wv.y; acc[0][2] += xv.x * wv.z; acc[0][3] += xv.x * wv.w;
      acc[1][0] += xv.y * wv.x; acc[1][1] += xv.y * wv.y; acc[1][2] += xv.y * wv.z; acc[1][3] += xv.y * wv.w;
      acc[2][0] += xv.z * wv.x; acc[2][1] += xv.z * wv.y; acc[2][2] += xv.z * wv.z; acc[2][3] += xv.z * wv.w;
      acc[3][0] += xv.w * wv.x; acc[3][1] += xv.w * wv.y; acc[3][2] += xv.w * wv.z; acc[3][3] += xv.w * wv.w;
    }
#pragma unroll
    for (int jj = 0; jj < 4; jj++) {
      int f = f0 + jj;
      float bb = b0[f];
      float4 v = make_float4(fmaxf(acc[0][jj] + bb, 0.f), fmaxf(acc[1][jj] + bb, 0.f),
                             fmaxf(acc[2][jj] + bb, 0.f), fmaxf(acc[3][jj] + bb, 0.f));
      *(float4*)(&tst[f][r0]) = v;  // once per kernel; conflicts negligible
    }
  }
  __syncthreads();

  // GEMM2 (K-split x4) -> part
  {
    int c0 = (tid & 31) << 2;
    int r0 = ((tid >> 5) & 1) << 2;
    int kq = tid >> 6;
    float acc[4][4];
#pragma unroll
    for (int i = 0; i < 4; i++)
#pragma unroll
      for (int jj = 0; jj < 4; jj++) acc[i][jj] = 0.f;
    const float* W1p = W1 + (size_t)kq * 128 * 128;
    const float(*tstp)[12] = &tst[kq * 128];
#pragma unroll 4
    for (int t = 0; t < 128; t++) {
      float4 wv = *(const float4*)(W1p + t * 128 + c0);
      float4 tv = *(const float4*)(&tstp[t][r0]);
      acc[0][0] += tv.x * wv.x; acc[0][1] += tv.x * wv.y; acc[0][2] += tv.x * wv.z; acc[0][3] += tv.x * wv.w;
      acc[1][0] += tv.y * wv.x; acc[1][1] += tv.y * wv.y; acc[1][2] += tv.y * wv.z; acc[1][3] += tv.y * wv.w;
      acc[2][0] += tv.z * wv.x; acc[2][1] += tv.z * wv.y; acc[2][2] += tv.z * wv.z; acc[2][3] += tv.z * wv.w;
      acc[3][0] += tv.w * wv.x; acc[3][1] += tv.w * wv.y; acc[3][2] += tv.w * wv.z; acc[3][3] += tv.w * wv.w;
    }
#pragma unroll
    for (int i = 0; i < 4; i++) {
      *(float4*)(&part[kq][r0 + i][c0]) =
          make_float4(acc[i][0], acc[i][1], acc[i][2], acc[i][3]);
    }
  }
  __syncthreads();

  for (int idx = tid; idx < 1024; idx += 256) {
    int r = idx >> 7, c = idx & 127;
    ys[r][c] = part[0][r][c] + part[1][r][c] + part[2][r][c] + part[3][r][c] +
               b1[c] + xst[c][r];
  }
  __syncthreads();

  int w = tid >> 6, lane = tid & 63;
#pragma unroll
  for (int rr = 2 * w; rr <= 2 * w + 1; rr++) {
    float a0 = ys[rr][lane], a1 = ys[rr][lane + 64];
    float s = a0 + a1, s2 = a0 * a0 + a1 * a1;
    for (int o = 32; o > 0; o >>= 1) {
      s += __shfl_xor(s, o, 64);
      s2 += __shfl_xor(s2, o, 64);
    }
    float mu = s * (1.f / 128.f);
    float var = s2 * (1.f / 128.f) - mu * mu;
    float rs = rsqrtf(var + 1e-5f);
    ys[rr][lane] = (a0 - mu) * rs * g1[lane] + be1[lane];
    ys[rr][lane + 64] = (a1 - mu) * rs * g1[lane + 64] + be1[lane + 64];
  }
  __syncthreads();

  {
    int c = tid >> 1, t = tid & 1;
    int n = (int)(rbase >> 9);
    int l0 = (int)(rbase & 511);
    float4 v = make_float4(ys[4 * t + 0][c], ys[4 * t + 1][c],
                           ys[4 * t + 2][c], ys[4 * t + 3][c]);
    *(float4*)(out + ((size_t)n * 128 + c) * 512 + l0 + 4 * t) = v;
  }
}

// ---------------------------------------------------------------------------
extern "C" void kernel_launch(void* const* d_in, const int* in_sizes, int n_in,
                              void* d_out, int out_size, void* d_ws, size_t ws_size,
                              hipStream_t stream) {
  const float* x   = (const float*)d_in[0];
  const float* Wx  = (const float*)d_in[1];
  const float* Wt  = (const float*)d_in[2];
  const float* bh  = (const float*)d_in[3];
  const float* Wa  = (const float*)d_in[4];
  const float* ba  = (const float*)d_in[5];
  const float* W0  = (const float*)d_in[6];
  const float* b0  = (const float*)d_in[7];
  const float* W1  = (const float*)d_in[8];
  const float* b1  = (const float*)d_in[9];
  const float* g0  = (const float*)d_in[10];
  const float* be0 = (const float*)d_in[11];
  const float* g1  = (const float*)d_in[12];
  const float* be1 = (const float*)d_in[13];

  float* outx = (float*)d_out;           // N*C*L = 524288
  float* outa = outx + (size_t)524288;   // N*L*L = 2097152

  float* ws = (float*)d_ws;
  float* xt = ws;              // 524288
  float* q  = xt + 524288;     // 262144
  float* k  = q + 262144;      // 262144
  float* x2 = k + 262144;      // 524288

  prep_kernel<<<256, 256, 0, stream>>>(x, Wt, Wx, xt, q, k);
  attn_fused_kernel<<<1024, 256, 0, stream>>>(q, k, bh, Wa, ba, xt, g0, be0,
                                              outa, x2);
  ffn_ln_kernel<<<512, 256, 0, stream>>>(x2, W0, b0, W1, b1, g1, be1, outx);
}

// Round 5
// 141.988 us; speedup vs baseline: 1.0054x; 1.0054x over previous
//
#include <hip/hip_runtime.h>
#include <cstddef>

// N=8, C=128, L=512, D=64, F=512, ATTN_W=64

// ---------------------------------------------------------------------------
// Kernel 1: prep = transpose_in + q/k projection. grid 512, block 256.
// Block = (n, l-tile of 16, which). which=0: q via Wt (+ xt write); which=1: k.
// 2 blocks/CU -> 2 waves/SIMD (vs 1 before).
// ---------------------------------------------------------------------------
__global__ __launch_bounds__(256) void prep_kernel(
    const float* __restrict__ x, const float* __restrict__ Wt,
    const float* __restrict__ Wx, float* __restrict__ xt,
    float* __restrict__ q, float* __restrict__ k) {
  __shared__ float xs[128][17];
  int tid = threadIdx.x;
  int bz = blockIdx.x;
  int n = bz >> 6;
  int t6 = bz & 63;
  int l0 = (t6 >> 1) << 4;
  int which = t6 & 1;

  for (int idx = tid; idx < 512; idx += 256) {
    int c = idx >> 2, v = idx & 3;
    float4 d4 = *(const float4*)(x + ((size_t)n * 128 + c) * 512 + l0 + 4 * v);
    xs[c][4 * v + 0] = d4.x; xs[c][4 * v + 1] = d4.y;
    xs[c][4 * v + 2] = d4.z; xs[c][4 * v + 3] = d4.w;
  }
  __syncthreads();

  if (which == 0) {
    for (int idx = tid; idx < 2048; idx += 256) {
      int c = idx & 127, jj = idx >> 7;
      xt[((size_t)n * 512 + l0 + jj) * 128 + c] = xs[c][jj];
    }
  }

  const float* W = which ? Wx : Wt;
  float* dst = which ? k : q;
  int r = tid >> 4;          // 0..15
  int f0 = (tid & 15) << 2;  // 0..60
  float acc[4] = {0.f, 0.f, 0.f, 0.f};
#pragma unroll 4
  for (int cc = 0; cc < 128; cc++) {
    float xv = xs[cc][r];
    float4 w = *(const float4*)(W + cc * 64 + f0);
    acc[0] += xv * w.x; acc[1] += xv * w.y;
    acc[2] += xv * w.z; acc[3] += xv * w.w;
  }
  *(float4*)(dst + ((size_t)n * 512 + l0 + r) * 64 + f0) =
      make_float4(acc[0], acc[1], acc[2], acc[3]);
}

// ---------------------------------------------------------------------------
// Kernel 2: FUSED banded attention scores + softmax + a-write + v=a@xt +
// residual + LN0 -> x2. grid 1024 (= N*L/4), block 256.
// In-band max valid: denom >= 1, eps rescale error ~1e-5 << threshold.
// ---------------------------------------------------------------------------
__global__ __launch_bounds__(256) void attn_fused_kernel(
    const float* __restrict__ q, const float* __restrict__ k,
    const float* __restrict__ bh, const float* __restrict__ Wa,
    const float* __restrict__ ba, const float* __restrict__ xt,
    const float* __restrict__ g0, const float* __restrict__ be0,
    float* __restrict__ a, float* __restrict__ x2) {
  __shared__ float ks[67][65];
  __shared__ float qs[4][64];
  __shared__ float was[64];
  __shared__ float av[4][64];
  __shared__ float ys[4][128];
  int tid = threadIdx.x;
  int w = tid >> 6, lane = tid & 63;
  int n = blockIdx.x >> 7;
  int i0 = (blockIdx.x & 127) << 2;
  int i = i0 + w;
  int jlo0 = i0 - 32;

  if (tid < 64) was[tid] = Wa[tid];
  qs[w][lane] = q[((size_t)n * 512 + i) * 64 + lane] + bh[lane];

  for (int idx = tid; idx < 67 * 64; idx += 256) {
    int row = idx >> 6, d = idx & 63;
    int j = jlo0 + row;
    ks[row][d] = (j >= 0 && j < 512) ? k[((size_t)n * 512 + j) * 64 + d] : 0.f;
  }
  __syncthreads();

  int j = jlo0 + w + lane;
  bool valid = (j >= 0 && j < 512);
  const float* krow = &ks[w + lane][0];
  float e = 0.f;
#pragma unroll 8
  for (int d = 0; d < 64; d++) {
    float hx = qs[w][d] + krow[d];
    float ex2 = __expf(2.f * hx);
    float th = 1.f - 2.f * __builtin_amdgcn_rcpf(ex2 + 1.f);  // tanh
    e += was[d] * th;
  }
  e += ba[0];
  if (!valid) e = -1e30f;

  float m = e;
  for (int o = 32; o > 0; o >>= 1) m = fmaxf(m, __shfl_xor(m, o, 64));
  float ex = valid ? __expf(e - m) : 0.f;
  float s = ex;
  for (int o = 32; o > 0; o >>= 1) s += __shfl_xor(s, o, 64);
  av[w][lane] = ex / (s + 1e-6f);

  {
    float* arow = a + ((size_t)n * 512 + i) * 512;
    int jlo = i - 32;
#pragma unroll
    for (int t = 0; t < 2; t++) {
      int col0 = 4 * lane + 256 * t;
      float4 v;
      { int jr = col0 + 0 - jlo; int jc = min(max(jr, 0), 63); v.x = (jr >= 0 && jr < 64) ? av[w][jc] : 0.f; }
      { int jr = col0 + 1 - jlo; int jc = min(max(jr, 0), 63); v.y = (jr >= 0 && jr < 64) ? av[w][jc] : 0.f; }
      { int jr = col0 + 2 - jlo; int jc = min(max(jr, 0), 63); v.z = (jr >= 0 && jr < 64) ? av[w][jc] : 0.f; }
      { int jr = col0 + 3 - jlo; int jc = min(max(jr, 0), 63); v.w = (jr >= 0 && jr < 64) ? av[w][jc] : 0.f; }
      *(float4*)(arow + col0) = v;
    }
  }
  __syncthreads();

  {
    int c = tid & 127;
    int h = tid >> 7;
    int r0 = 2 * h;
    const float* xtn = xt + (size_t)n * 512 * 128;
    float acc0 = 0.f, acc1 = 0.f;
    float res0 = 0.f, res1 = 0.f;
#pragma unroll 8
    for (int mm = 0; mm <= 64; mm++) {
      int jj = jlo0 + r0 + mm;
      int jc = min(max(jj, 0), 511);
      float xv = xtn[(size_t)jc * 128 + c];
      if (mm == 32) res0 = xv;
      if (mm == 33) res1 = xv;
      if (mm < 64) acc0 += av[r0][mm] * xv;
      if (mm >= 1) acc1 += av[r0 + 1][mm - 1] * xv;
    }
    ys[r0][c] = acc0 + res0;
    ys[r0 + 1][c] = acc1 + res1;
  }
  __syncthreads();

  {
    float a0 = ys[w][lane], a1 = ys[w][lane + 64];
    float s0 = a0 + a1, s2 = a0 * a0 + a1 * a1;
    for (int o = 32; o > 0; o >>= 1) {
      s0 += __shfl_xor(s0, o, 64);
      s2 += __shfl_xor(s2, o, 64);
    }
    float mu = s0 * (1.f / 128.f);
    float var = s2 * (1.f / 128.f) - mu * mu;
    float rs = rsqrtf(var + 1e-5f);
    float* xrow = x2 + ((size_t)n * 512 + i) * 128;
    xrow[lane] = (a0 - mu) * rs * g0[lane] + be0[lane];
    xrow[lane + 64] = (a1 - mu) * rs * g0[lane + 64] + be0[lane + 64];
  }
}

// ---------------------------------------------------------------------------
// Kernel 3: FFN + residual + LN1 + transposed write -> out (N,C,L).
// 16 rows/block, grid 256, block 512 (halves W0/W1 L2 traffic vs 8-row).
// GEMM1: strided-f 4r x 4f (scalar W0 loads -> benign LDS write pattern).
// GEMM2: K-split x4 across thread quarters, LDS partial reduce.
// ---------------------------------------------------------------------------
__global__ __launch_bounds__(512, 2) void ffn_ln_kernel(
    const float* __restrict__ x2, const float* __restrict__ W0,
    const float* __restrict__ b0, const float* __restrict__ W1,
    const float* __restrict__ b1, const float* __restrict__ g1,
    const float* __restrict__ be1, float* __restrict__ out) {
  __shared__ float xst[128][20];   // [c][r], stride 20: float4-aligned
  __shared__ float tst[512][20];   // [f][r] relu(GEMM1)
  __shared__ float part[4][16][128];
  __shared__ float ys[16][128];
  int tid = threadIdx.x;
  size_t rbase = (size_t)blockIdx.x * 16;

  for (int idx = tid; idx < 2048; idx += 512) {
    int r = idx >> 7, c = idx & 127;
    xst[c][r] = x2[(rbase + r) * 128 + c];
  }
  __syncthreads();

  // GEMM1 + bias + relu -> tst. Thread = rows r0..r0+3 x f in {fb+128j}.
  {
    int fb = tid & 127;
    int r0 = (tid >> 7) << 2;   // 0,4,8,12
    float acc[4][4];
#pragma unroll
    for (int i = 0; i < 4; i++)
#pragma unroll
      for (int jj = 0; jj < 4; jj++) acc[i][jj] = 0.f;
#pragma unroll 4
    for (int cc = 0; cc < 128; cc++) {
      float4 xv = *(const float4*)(&xst[cc][r0]);   // broadcast (4 addrs)
      float w0 = W0[cc * 512 + fb];
      float w1 = W0[cc * 512 + fb + 128];
      float w2 = W0[cc * 512 + fb + 256];
      float w3 = W0[cc * 512 + fb + 384];
      acc[0][0] += xv.x * w0; acc[1][0] += xv.y * w0; acc[2][0] += xv.z * w0; acc[3][0] += xv.w * w0;
      acc[0][1] += xv.x * w1; acc[1][1] += xv.y * w1; acc[2][1] += xv.z * w1; acc[3][1] += xv.w * w1;
      acc[0][2] += xv.x * w2; acc[1][2] += xv.y * w2; acc[2][2] += xv.z * w2; acc[3][2] += xv.w * w2;
      acc[0][3] += xv.x * w3; acc[1][3] += xv.y * w3; acc[2][3] += xv.z * w3; acc[3][3] += xv.w * w3;
    }
#pragma unroll
    for (int jj = 0; jj < 4; jj++) {
      int f = fb + 128 * jj;
      float bb = b0[f];
      float4 v = make_float4(fmaxf(acc[0][jj] + bb, 0.f), fmaxf(acc[1][jj] + bb, 0.f),
                             fmaxf(acc[2][jj] + bb, 0.f), fmaxf(acc[3][jj] + bb, 0.f));
      *(float4*)(&tst[f][r0]) = v;
    }
  }
  __syncthreads();

  // GEMM2 (K-split x4) -> part. Quarter kq of 128 threads: 4r x 4c each.
  {
    int kq = tid >> 7;               // 0..3
    int c0 = (tid & 31) << 2;        // 0..124
    int r0 = ((tid >> 5) & 3) << 2;  // 0,4,8,12
    float acc[4][4];
#pragma unroll
    for (int i = 0; i < 4; i++)
#pragma unroll
      for (int jj = 0; jj < 4; jj++) acc[i][jj] = 0.f;
    const float* W1p = W1 + (size_t)kq * 128 * 128;
    const float(*tstp)[20] = &tst[kq * 128];
#pragma unroll 4
    for (int t = 0; t < 128; t++) {
      float4 wv = *(const float4*)(W1p + t * 128 + c0);
      float4 tv = *(const float4*)(&tstp[t][r0]);   // broadcast (4 addrs)
      acc[0][0] += tv.x * wv.x; acc[0][1] += tv.x * wv.y; acc[0][2] += tv.x * wv.z; acc[0][3] += tv.x * wv.w;
      acc[1][0] += tv.y * wv.x; acc[1][1] += tv.y * wv.y; acc[1][2] += tv.y * wv.z; acc[1][3] += tv.y * wv.w;
      acc[2][0] += tv.z * wv.x; acc[2][1] += tv.z * wv.y; acc[2][2] += tv.z * wv.z; acc[2][3] += tv.z * wv.w;
      acc[3][0] += tv.w * wv.x; acc[3][1] += tv.w * wv.y; acc[3][2] += tv.w * wv.z; acc[3][3] += tv.w * wv.w;
    }
#pragma unroll
    for (int i = 0; i < 4; i++) {
      *(float4*)(&part[kq][r0 + i][c0]) =
          make_float4(acc[i][0], acc[i][1], acc[i][2], acc[i][3]);
    }
  }
  __syncthreads();

  for (int idx = tid; idx < 2048; idx += 512) {
    int r = idx >> 7, c = idx & 127;
    ys[r][c] = part[0][r][c] + part[1][r][c] + part[2][r][c] + part[3][r][c] +
               b1[c] + xst[c][r];
  }
  __syncthreads();

  // LN1: 8 waves x 2 rows
  int w = tid >> 6, lane = tid & 63;
#pragma unroll
  for (int rr = 2 * w; rr <= 2 * w + 1; rr++) {
    float a0 = ys[rr][lane], a1 = ys[rr][lane + 64];
    float s = a0 + a1, s2 = a0 * a0 + a1 * a1;
    for (int o = 32; o > 0; o >>= 1) {
      s += __shfl_xor(s, o, 64);
      s2 += __shfl_xor(s2, o, 64);
    }
    float mu = s * (1.f / 128.f);
    float var = s2 * (1.f / 128.f) - mu * mu;
    float rs = rsqrtf(var + 1e-5f);
    ys[rr][lane] = (a0 - mu) * rs * g1[lane] + be1[lane];
    ys[rr][lane + 64] = (a1 - mu) * rs * g1[lane + 64] + be1[lane + 64];
  }
  __syncthreads();

  // transposed write: out (N,C,L); 16 consecutive l per c
  {
    int c = tid >> 2, tq = tid & 3;
    int n = (int)(rbase >> 9);
    int l0 = (int)(rbase & 511);
    float4 v = make_float4(ys[4 * tq + 0][c], ys[4 * tq + 1][c],
                           ys[4 * tq + 2][c], ys[4 * tq + 3][c]);
    *(float4*)(out + ((size_t)n * 128 + c) * 512 + l0 + 4 * tq) = v;
  }
}

// ---------------------------------------------------------------------------
extern "C" void kernel_launch(void* const* d_in, const int* in_sizes, int n_in,
                              void* d_out, int out_size, void* d_ws, size_t ws_size,
                              hipStream_t stream) {
  const float* x   = (const float*)d_in[0];
  const float* Wx  = (const float*)d_in[1];
  const float* Wt  = (const float*)d_in[2];
  const float* bh  = (const float*)d_in[3];
  const float* Wa  = (const float*)d_in[4];
  const float* ba  = (const float*)d_in[5];
  const float* W0  = (const float*)d_in[6];
  const float* b0  = (const float*)d_in[7];
  const float* W1  = (const float*)d_in[8];
  const float* b1  = (const float*)d_in[9];
  const float* g0  = (const float*)d_in[10];
  const float* be0 = (const float*)d_in[11];
  const float* g1  = (const float*)d_in[12];
  const float* be1 = (const float*)d_in[13];

  float* outx = (float*)d_out;           // N*C*L = 524288
  float* outa = outx + (size_t)524288;   // N*L*L = 2097152

  float* ws = (float*)d_ws;
  float* xt = ws;              // 524288
  float* q  = xt + 524288;     // 262144
  float* k  = q + 262144;      // 262144
  float* x2 = k + 262144;      // 524288

  prep_kernel<<<512, 256, 0, stream>>>(x, Wt, Wx, xt, q, k);
  attn_fused_kernel<<<1024, 256, 0, stream>>>(q, k, bh, Wa, ba, xt, g0, be0,
                                              outa, x2);
  ffn_ln_kernel<<<256, 512, 0, stream>>>(x2, W0, b0, W1, b1, g1, be1, outx);
}